// Round 10
// baseline (5508.153 us; speedup 1.0000x reference)
//
#include <hip/hip_runtime.h>
#include <hip/hip_bf16.h>

typedef __attribute__((ext_vector_type(8))) short short8;
typedef __attribute__((ext_vector_type(4))) float f32x4;
typedef unsigned long long u64;

#define MFMA16(A, B, C) __builtin_amdgcn_mfma_f32_16x16x32_bf16((A), (B), (C), 0, 0, 0)

static constexpr int kS = 512;   // seq
static constexpr int kI = 256;   // in_dim
static constexpr int kH = 2048;  // hidden
static constexpr int kC = 1024;  // classes
static constexpr int kBt = 256;  // batch
static constexpr int kHQ = kBt * kH / 4;  // u64s per h buffer (1 MB)

// WG tile: 32 batch rows x 64 hidden cols. Grid 256 = 8 rowgroups x 32 colgroups.
// Control skeleton == R7 (4542us validated): wave0-only LLC flag poll,
// 3 __syncthreads/step, single zone, agent-scope flag/store intrinsics.
// NEW: h rotates through nbuf >= 16 buffers -> a consumer's L1/L2 cannot hold
// a stale line for the buffer being read (last touched nbuf steps ago; ~1.25
// MB/step/XCD of L2 fills evicts it), so staging uses PLAIN CACHED loads:
// per-XCD L2 dedupes the ~4 same-rowgroup WGs and fills ride cache lines.
// h stores stay sc0sc1 (LLC = coherence point). If ws_size is too small for
// 16 buffers -> cached=0 -> exact R7 ping-pong sc0sc1 path.
// LDS map (dynamic, 139264 B):
//   [0,      131072): h-stage [32 rows][2048 k] bf16, stride 4096 B, XOR swizzle
//                     (epilogue reuse: Wph^T [32 cls-cols][2048 k])
//   [131072, 139264): K-half zone [32 rows][16 quads f32x4], XOR swizzle
static constexpr int ZONE_OFF = 131072;

__device__ __forceinline__ int swz(int row, int kbyte) {
  return row * 4096 + (kbyte ^ ((row & 7) << 4));
}
__device__ __forceinline__ f32x4* zslot(char* smem, int row, int quad) {
  return (f32x4*)(smem + ZONE_OFF + row * 256 + (((quad ^ row) & 15) << 4));
}
__device__ __forceinline__ f32x4* zslot2(char* smem, int row, int quad) {  // epilogue
  return (f32x4*)(smem + ZONE_OFF + row * 128 + (((quad ^ row) & 7) << 4));
}

__device__ __forceinline__ unsigned short f2bf(float f) {  // RNE fp32->bf16
  unsigned u = __float_as_uint(f);
  u += 0x7fffu + ((u >> 16) & 1u);
  return (unsigned short)(u >> 16);
}

__device__ __forceinline__ float fast_tanh(float v) {
  float a = __builtin_fabsf(v);
  float e = __expf(-2.0f * a);
  float r = (1.0f - e) / (1.0f + e);
  return __builtin_copysignf(r, v);
}

// Validated LLC-coherent intrinsic path (rounds 2-5, 7).
__device__ __forceinline__ u64 ld_h8(const u64* p) {
  return __hip_atomic_load(p, __ATOMIC_RELAXED, __HIP_MEMORY_SCOPE_AGENT);
}
__device__ __forceinline__ void st_h8(u64* p, u64 v) {
  __hip_atomic_store(p, v, __ATOMIC_RELAXED, __HIP_MEMORY_SCOPE_AGENT);
}
__device__ __forceinline__ unsigned ld_flag(const unsigned* p) {
  return __hip_atomic_load(p, __ATOMIC_RELAXED, __HIP_MEMORY_SCOPE_AGENT);
}
__device__ __forceinline__ void st_flag(unsigned* p, unsigned v) {
  __hip_atomic_store(p, v, __ATOMIC_RELAXED, __HIP_MEMORY_SCOPE_AGENT);
}

// 16 x 16B loads in flight, counted-vmcnt split (R9's staging form, kept).
#define STAGE16(CPOL) do {                                                   \
  f32x4 a0, a1, a2, a3, a4, a5, a6, a7, b0, b1, b2, b3, b4, b5, b6, b7;      \
  asm volatile(                                                              \
      "global_load_dwordx4 %0, %16, off" CPOL "\n\t"                         \
      "global_load_dwordx4 %1, %16, off offset:256" CPOL "\n\t"              \
      "global_load_dwordx4 %2, %16, off offset:512" CPOL "\n\t"              \
      "global_load_dwordx4 %3, %16, off offset:768" CPOL "\n\t"              \
      "global_load_dwordx4 %4, %16, off offset:1024" CPOL "\n\t"             \
      "global_load_dwordx4 %5, %16, off offset:1280" CPOL "\n\t"             \
      "global_load_dwordx4 %6, %16, off offset:1536" CPOL "\n\t"             \
      "global_load_dwordx4 %7, %16, off offset:1792" CPOL "\n\t"             \
      "global_load_dwordx4 %8, %16, off offset:2048" CPOL "\n\t"             \
      "global_load_dwordx4 %9, %16, off offset:2304" CPOL "\n\t"             \
      "global_load_dwordx4 %10, %16, off offset:2560" CPOL "\n\t"            \
      "global_load_dwordx4 %11, %16, off offset:2816" CPOL "\n\t"            \
      "global_load_dwordx4 %12, %16, off offset:3072" CPOL "\n\t"            \
      "global_load_dwordx4 %13, %16, off offset:3328" CPOL "\n\t"            \
      "global_load_dwordx4 %14, %16, off offset:3584" CPOL "\n\t"            \
      "global_load_dwordx4 %15, %16, off offset:3840" CPOL                   \
      : "=&v"(a0), "=&v"(a1), "=&v"(a2), "=&v"(a3),                          \
        "=&v"(a4), "=&v"(a5), "=&v"(a6), "=&v"(a7),                          \
        "=&v"(b0), "=&v"(b1), "=&v"(b2), "=&v"(b3),                          \
        "=&v"(b4), "=&v"(b5), "=&v"(b6), "=&v"(b7)                           \
      : "v"(hp) : "memory");                                                 \
  asm volatile("s_waitcnt vmcnt(8)" ::: "memory");                           \
  __builtin_amdgcn_sched_barrier(0);                                         \
  *(f32x4*)(smem + swz(srow, kb0))        = a0;                              \
  *(f32x4*)(smem + swz(srow, kb0 + 256))  = a1;                              \
  *(f32x4*)(smem + swz(srow, kb0 + 512))  = a2;                              \
  *(f32x4*)(smem + swz(srow, kb0 + 768))  = a3;                              \
  *(f32x4*)(smem + swz(srow, kb0 + 1024)) = a4;                              \
  *(f32x4*)(smem + swz(srow, kb0 + 1280)) = a5;                              \
  *(f32x4*)(smem + swz(srow, kb0 + 1536)) = a6;                              \
  *(f32x4*)(smem + swz(srow, kb0 + 1792)) = a7;                              \
  asm volatile("s_waitcnt vmcnt(0)" ::: "memory");                           \
  __builtin_amdgcn_sched_barrier(0);                                         \
  *(f32x4*)(smem + swz(srow, kb0 + 2048)) = b0;                              \
  *(f32x4*)(smem + swz(srow, kb0 + 2304)) = b1;                              \
  *(f32x4*)(smem + swz(srow, kb0 + 2560)) = b2;                              \
  *(f32x4*)(smem + swz(srow, kb0 + 2816)) = b3;                              \
  *(f32x4*)(smem + swz(srow, kb0 + 3072)) = b4;                              \
  *(f32x4*)(smem + swz(srow, kb0 + 3328)) = b5;                              \
  *(f32x4*)(smem + swz(srow, kb0 + 3584)) = b6;                              \
  *(f32x4*)(smem + swz(srow, kb0 + 3840)) = b7;                              \
} while (0)

__global__ __launch_bounds__(512, 2)
void rnn_fused(const float* __restrict__ x, const float* __restrict__ Whx,
               const float* __restrict__ Whh, const float* __restrict__ Wph,
               const float* __restrict__ Bh, const float* __restrict__ Bp,
               float* __restrict__ out,
               u64* __restrict__ hbase, unsigned* __restrict__ flags,
               int bmask, int cached) {
  extern __shared__ char smem[];
  const int tid = (int)threadIdx.x;
  const int lane = tid & 63;
  const int wv = tid >> 6;       // 0..7
  const int ci = wv & 3;         // 16-col group within WG
  const int kh = wv >> 2;        // K-half (0/1)
  const int wg = (int)blockIdx.x;
  const int rg = wg >> 5;        // 0..7  : rowgroup (32 rows, barrier domain)
  const int cg = wg & 31;        // 0..31 : colgroup (64 hidden cols)
  const int r0 = rg * 32;
  const int n0 = cg * 64;

  const int brow = lane & 15;    // batch row within 16-row tile; also A-row
  const int nq = lane >> 4;      // k-segment / D col-quad
  const int klo = nq * 8;
  const int wcol = n0 + ci * 16 + brow;   // this lane's hidden col (A operand)

  // ---- persistent A fragments in VGPRs (one-time gather, cached path)
  short8 wa[32];  // Whh^T: 16 cols x 1024 k (this wave's K-half)
#pragma unroll
  for (int kt = 0; kt < 32; ++kt) {
    const float* wp = Whh + (size_t)(kh * 1024 + kt * 32 + klo) * kH + wcol;
#pragma unroll
    for (int jj = 0; jj < 8; ++jj) wa[kt][jj] = (short)f2bf(wp[(size_t)jj * kH]);
  }
  short8 wx[4];   // Whx^T: 16 cols x 128 k (K-half of 256)
#pragma unroll
  for (int kt = 0; kt < 4; ++kt) {
    const float* wp = Whx + (size_t)(kh * 128 + kt * 32 + klo) * kH + wcol;
#pragma unroll
    for (int jj = 0; jj < 8; ++jj) wx[kt][jj] = (short)f2bf(wp[(size_t)jj * kH]);
  }

  const f32x4 bh = *(const f32x4*)(Bh + n0 + ci * 16 + nq * 4);

  // stage geometry: thread -> (row, 16B chunks at sc16*16 + j*256)
  const int srow = tid >> 4;     // 0..31
  const int kb0 = (tid & 15) * 16;

  unsigned* gflags = flags + (rg << 5);  // 32 flags per rowgroup
  const float* pxA = x + (size_t)(r0 + brow) * (kS * kI);
  const float* pxB = x + (size_t)(r0 + 16 + brow) * (kS * kI);

  for (int t = 0; t < kS; ++t) {
    const u64* hc = hbase + (size_t)(t & bmask) * kHQ;
    u64* hn       = hbase + (size_t)((t + 1) & bmask) * kHQ;
    f32x4 acc0 = {0.f, 0.f, 0.f, 0.f};
    f32x4 acc1 = {0.f, 0.f, 0.f, 0.f};

    // ---- x_t @ Whx over this wave's K-half (no h dep: overlaps flag wait)
#pragma unroll
    for (int kt = 0; kt < 4; ++kt) {
      const int k = kh * 128 + kt * 32 + klo;
      f32x4 xa = *(const f32x4*)(pxA + (size_t)t * kI + k);
      f32x4 xb = *(const f32x4*)(pxA + (size_t)t * kI + k + 4);
      f32x4 ya = *(const f32x4*)(pxB + (size_t)t * kI + k);
      f32x4 yb = *(const f32x4*)(pxB + (size_t)t * kI + k + 4);
      short8 b0, b1;
#pragma unroll
      for (int jj = 0; jj < 4; ++jj) {
        b0[jj] = (short)f2bf(xa[jj]); b0[jj + 4] = (short)f2bf(xb[jj]);
        b1[jj] = (short)f2bf(ya[jj]); b1[jj + 4] = (short)f2bf(yb[jj]);
      }
      acc0 = MFMA16(wx[kt], b0, acc0);
      acc1 = MFMA16(wx[kt], b1, acc1);
    }

    // ---- wait for h_t: only wave 0 polls (validated LLC flag protocol)
    if (t > 0 && wv == 0) {
      while (!__all((int)(ld_flag(&gflags[lane & 31]) >= (unsigned)t)))
        __builtin_amdgcn_s_sleep(2);
      asm volatile("" ::: "memory");
    }
    __syncthreads();

    // ---- cooperative stage: h[32 x 2048] -> LDS, 16 loads in flight.
    // cached: plain loads (L2 dedupes same-rowgroup WGs; rotation guarantees
    // no stale line). uncached fallback: sc0sc1 LLC path (== R7).
    {
      const char* hp = (const char*)hc + (size_t)(r0 + srow) * 4096 + kb0;
      if (cached) STAGE16("");
      else        STAGE16(" sc0 sc1");
    }
    __syncthreads();

    // ---- h_t @ Whh: A from VGPR, B from swizzled LDS
#pragma unroll
    for (int kt = 0; kt < 32; ++kt) {
      const int kb = (kh * 1024 + kt * 32 + klo) * 2;
      short8 hb0 = *(const short8*)(smem + swz(brow, kb));
      short8 hb1 = *(const short8*)(smem + swz(brow + 16, kb));
      acc0 = MFMA16(wa[kt], hb0, acc0);
      acc1 = MFMA16(wa[kt], hb1, acc1);
    }

    // ---- K-half handoff (non-atomic zone; one owner per slot)
    if (kh == 1) {
      *zslot(smem, brow, ci * 4 + nq) = acc0;
      *zslot(smem, brow + 16, ci * 4 + nq) = acc1;
    }
    __syncthreads();

    // ---- kh==0: combine halves, tanh, pack 4 bf16 -> one 8B LLC store per tile
    if (kh == 0) {
      f32x4 s0 = *zslot(smem, brow, ci * 4 + nq);
      f32x4 s1 = *zslot(smem, brow + 16, ci * 4 + nq);
      u64 v0 = 0, v1 = 0;
#pragma unroll
      for (int jj = 0; jj < 4; ++jj) {
        v0 |= (u64)f2bf(fast_tanh(acc0[jj] + s0[jj] + bh[jj])) << (16 * jj);
        v1 |= (u64)f2bf(fast_tanh(acc1[jj] + s1[jj] + bh[jj])) << (16 * jj);
      }
      const int qoff = (n0 >> 2) + ci * 4 + nq;
      st_h8(hn + (size_t)(r0 + brow) * 512 + qoff, v0);
      st_h8(hn + (size_t)(r0 + 16 + brow) * 512 + qoff, v1);
    }

    // ---- release: __syncthreads drains each wave's vmcnt (stores ack'd at LLC)
    __syncthreads();
    if (tid == 0) st_flag(&gflags[cg], (unsigned)(t + 1));
  }

  // ================= epilogue: out = h_final @ Wph + Bp =================
  if (wv == 0) {
    while (!__all((int)(ld_flag(&gflags[lane & 31]) >= (unsigned)kS)))
      __builtin_amdgcn_s_sleep(2);
    asm volatile("" ::: "memory");
  }
  __syncthreads();

  // stage Wph^T slice [32 cls-cols][2048 k] into h-stage region
  {
    const int c = tid & 31;
    const int kk = tid >> 5;  // 16 k-stripes
    for (int k = kk; k < kH; k += 16)
      *(unsigned short*)(smem + swz(c, k * 2)) = f2bf(Wph[(size_t)k * kC + cg * 32 + c]);
  }
  __syncthreads();

  // waves 0..3 active: (ci2 = wv&1 -> 16 cls-cols, kh2 = wv>>1 -> K-half)
  const u64* hfin = hbase + (size_t)(kS & bmask) * kHQ;  // 512 % nbuf == 0 -> buf[0]
  const bool act = (wv < 4);
  const int ci2 = wv & 1;
  const int kh2 = (wv >> 1) & 1;
  f32x4 oacc0 = {0.f, 0.f, 0.f, 0.f};
  f32x4 oacc1 = {0.f, 0.f, 0.f, 0.f};
  if (act) {
    const u64* phA = hfin + (size_t)(r0 + brow) * 512;
    const u64* phB = hfin + (size_t)(r0 + 16 + brow) * 512;
#pragma unroll 8
    for (int kt = 0; kt < 32; ++kt) {
      const int gk = kh2 * 1024 + kt * 32 + klo;
      short8 a = *(const short8*)(smem + swz(ci2 * 16 + brow, gk * 2));
      union { u64 q[2]; short8 s; } uA, uB;
      uA.q[0] = ld_h8(phA + (gk >> 2)); uA.q[1] = ld_h8(phA + (gk >> 2) + 1);
      uB.q[0] = ld_h8(phB + (gk >> 2)); uB.q[1] = ld_h8(phB + (gk >> 2) + 1);
      oacc0 = MFMA16(a, uA.s, oacc0);
      oacc1 = MFMA16(a, uB.s, oacc1);
    }
  }
  if (act && kh2 == 1) {
    *zslot2(smem, brow, ci2 * 4 + nq) = oacc0;
    *zslot2(smem, brow + 16, ci2 * 4 + nq) = oacc1;
  }
  __syncthreads();
  if (act && kh2 == 0) {
    f32x4 s0 = *zslot2(smem, brow, ci2 * 4 + nq);
    f32x4 s1 = *zslot2(smem, brow + 16, ci2 * 4 + nq);
    const int ocol = cg * 32 + ci2 * 16 + nq * 4;
    const f32x4 bp = *(const f32x4*)(Bp + ocol);
#pragma unroll
    for (int jj = 0; jj < 4; ++jj) {
      out[(size_t)(r0 + brow) * kC + ocol + jj] = oacc0[jj] + s0[jj] + bp[jj];
      out[(size_t)(r0 + 16 + brow) * kC + ocol + jj] = oacc1[jj] + s1[jj] + bp[jj];
    }
  }
}

extern "C" void kernel_launch(void* const* d_in, const int* in_sizes, int n_in,
                              void* d_out, int out_size, void* d_ws, size_t ws_size,
                              hipStream_t stream) {
  const float* x   = (const float*)d_in[0];
  const float* Whx = (const float*)d_in[1];
  const float* Whh = (const float*)d_in[2];
  const float* Wph = (const float*)d_in[3];
  const float* Bh  = (const float*)d_in[4];
  const float* Bp  = (const float*)d_in[5];
  float* out = (float*)d_out;

  const size_t HB = (size_t)kBt * kH * 2;  // 1 MB per h buffer
  int nbuf, cached;
  if      (ws_size >= 64 * HB + 4096) { nbuf = 64; cached = 1; }
  else if (ws_size >= 32 * HB + 4096) { nbuf = 32; cached = 1; }
  else if (ws_size >= 16 * HB + 4096) { nbuf = 16; cached = 1; }
  else                                { nbuf = 2;  cached = 0; }  // == R7

  char* ws = (char*)d_ws;
  u64* hbase      = (u64*)ws;
  unsigned* flags = (unsigned*)(ws + (size_t)nbuf * HB);

  hipMemsetAsync(hbase, 0, HB, stream);    // h_0 = 0 (buf[0])
  hipMemsetAsync(flags, 0, 4096, stream);  // reset barrier

  dim3 grid(256), block(512);
  size_t lds = 139264;  // 128K h-stage + 8K zone
  hipLaunchKernelGGL(rnn_fused, grid, block, lds, stream,
                     x, Whx, Whh, Wph, Bh, Bp, out, hbase, flags,
                     nbuf - 1, cached);
}

// Round 11
// 4107.429 us; speedup vs baseline: 1.3410x; 1.3410x over previous
//
#include <hip/hip_runtime.h>
#include <hip/hip_bf16.h>

typedef __attribute__((ext_vector_type(8))) short short8;
typedef __attribute__((ext_vector_type(4))) float f32x4;
typedef unsigned long long u64;

#define MFMA16(A, B, C) __builtin_amdgcn_mfma_f32_16x16x32_bf16((A), (B), (C), 0, 0, 0)

static constexpr int kS = 512;   // seq
static constexpr int kI = 256;   // in_dim
static constexpr int kH = 2048;  // hidden
static constexpr int kC = 1024;  // classes
static constexpr int kBt = 256;  // batch

// WG tile: 32 batch rows x 64 hidden cols. Grid 256 = 8 rowgroups x 32 colgroups.
// R7 control skeleton (4542us validated): wave0-only LLC flag poll, 3
// __syncthreads/step, single zone, agent-scope flag/h-store intrinsics,
// ping-pong h buffers. NEW vs R7: staging uses global_load_lds width=16
// (1 instr per wave per 1KB: 128 instrs/WG/step instead of 16384 load+ds_write)
// with PRE-SWIZZLED per-lane global addresses (LDS dest linear, rule #21) and
// CPol aux=17 (SC0|SC1) so consumer L1/L2 never cache h (same coherence point
// as R7's validated sc0sc1 loads).
// LDS map (dynamic, 139264 B):
//   [0,      131072): h-stage [32 rows][2048 k] bf16, stride 4096 B, XOR swizzle
//                     (epilogue reuse: Wph^T [32 cls-cols][2048 k])
//   [131072, 139264): K-half zone [32 rows][16 quads f32x4], XOR swizzle
static constexpr int ZONE_OFF = 131072;

__device__ __forceinline__ int swz(int row, int kbyte) {
  return row * 4096 + (kbyte ^ ((row & 7) << 4));
}
__device__ __forceinline__ f32x4* zslot(char* smem, int row, int quad) {
  return (f32x4*)(smem + ZONE_OFF + row * 256 + (((quad ^ row) & 15) << 4));
}
__device__ __forceinline__ f32x4* zslot2(char* smem, int row, int quad) {  // epilogue
  return (f32x4*)(smem + ZONE_OFF + row * 128 + (((quad ^ row) & 7) << 4));
}

__device__ __forceinline__ unsigned short f2bf(float f) {  // RNE fp32->bf16
  unsigned u = __float_as_uint(f);
  u += 0x7fffu + ((u >> 16) & 1u);
  return (unsigned short)(u >> 16);
}

__device__ __forceinline__ float fast_tanh(float v) {
  float a = __builtin_fabsf(v);
  float e = __expf(-2.0f * a);
  float r = (1.0f - e) / (1.0f + e);
  return __builtin_copysignf(r, v);
}

// Validated LLC-coherent intrinsic path (rounds 2-5, 7).
__device__ __forceinline__ u64 ld_h8(const u64* p) {
  return __hip_atomic_load(p, __ATOMIC_RELAXED, __HIP_MEMORY_SCOPE_AGENT);
}
__device__ __forceinline__ void st_h8(u64* p, u64 v) {
  __hip_atomic_store(p, v, __ATOMIC_RELAXED, __HIP_MEMORY_SCOPE_AGENT);
}
__device__ __forceinline__ unsigned ld_flag(const unsigned* p) {
  return __hip_atomic_load(p, __ATOMIC_RELAXED, __HIP_MEMORY_SCOPE_AGENT);
}
__device__ __forceinline__ void st_flag(unsigned* p, unsigned v) {
  __hip_atomic_store(p, v, __ATOMIC_RELAXED, __HIP_MEMORY_SCOPE_AGENT);
}

// Direct global->LDS DMA, 16B/lane, CPol aux=17 = SC0|SC1 (LLC coherence
// point, L1/L2 bypass). LDS dest is wave-uniform base + lane*16 (HW rule);
// the per-lane GLOBAL address carries the swizzle (m173 pattern).
__device__ __forceinline__ void gload_lds16(const void* g, void* l) {
  __builtin_amdgcn_global_load_lds(
      (const __attribute__((address_space(1))) void*)g,
      (__attribute__((address_space(3))) void*)l, 16, 0, 17);
}

__global__ __launch_bounds__(512, 2)
void rnn_fused(const float* __restrict__ x, const float* __restrict__ Whx,
               const float* __restrict__ Whh, const float* __restrict__ Wph,
               const float* __restrict__ Bh, const float* __restrict__ Bp,
               float* __restrict__ out,
               u64* __restrict__ h0buf, u64* __restrict__ h1buf,
               unsigned* __restrict__ flags) {
  extern __shared__ char smem[];
  const int tid = (int)threadIdx.x;
  const int lane = tid & 63;
  const int wv = tid >> 6;       // 0..7
  const int ci = wv & 3;         // 16-col group within WG
  const int kh = wv >> 2;        // K-half (0/1)
  const int wg = (int)blockIdx.x;
  const int rg = wg >> 5;        // 0..7  : rowgroup (32 rows, barrier domain)
  const int cg = wg & 31;        // 0..31 : colgroup (64 hidden cols)
  const int r0 = rg * 32;
  const int n0 = cg * 64;

  const int brow = lane & 15;    // batch row within 16-row tile; also A-row
  const int nq = lane >> 4;      // k-segment / D col-quad
  const int klo = nq * 8;
  const int wcol = n0 + ci * 16 + brow;   // this lane's hidden col (A operand)

  // ---- persistent A fragments in VGPRs (one-time gather, cached path)
  short8 wa[32];  // Whh^T: 16 cols x 1024 k (this wave's K-half)
#pragma unroll
  for (int kt = 0; kt < 32; ++kt) {
    const float* wp = Whh + (size_t)(kh * 1024 + kt * 32 + klo) * kH + wcol;
#pragma unroll
    for (int jj = 0; jj < 8; ++jj) wa[kt][jj] = (short)f2bf(wp[(size_t)jj * kH]);
  }
  short8 wx[4];   // Whx^T: 16 cols x 128 k (K-half of 256)
#pragma unroll
  for (int kt = 0; kt < 4; ++kt) {
    const float* wp = Whx + (size_t)(kh * 128 + kt * 32 + klo) * kH + wcol;
#pragma unroll
    for (int jj = 0; jj < 8; ++jj) wx[kt][jj] = (short)f2bf(wp[(size_t)jj * kH]);
  }

  const f32x4 bh = *(const f32x4*)(Bh + n0 + ci * 16 + nq * 4);

  // staging geometry: instr g = wv*16+j covers LDS row g>>2, quarter g&3;
  // lane's global byte = row*4096 + q*1024 + (lane*16 ^ ((row&7)<<4))
  const int laneoff = lane * 16;

  unsigned* gflags = flags + (rg << 5);  // 32 flags per rowgroup
  const float* pxA = x + (size_t)(r0 + brow) * (kS * kI);
  const float* pxB = x + (size_t)(r0 + 16 + brow) * (kS * kI);

  for (int t = 0; t < kS; ++t) {
    const u64* hc = (t & 1) ? h1buf : h0buf;
    u64* hn       = (t & 1) ? h0buf : h1buf;
    f32x4 acc0 = {0.f, 0.f, 0.f, 0.f};
    f32x4 acc1 = {0.f, 0.f, 0.f, 0.f};

    // ---- x_t @ Whx over this wave's K-half (no h dep: overlaps flag wait)
#pragma unroll
    for (int kt = 0; kt < 4; ++kt) {
      const int k = kh * 128 + kt * 32 + klo;
      f32x4 xa = *(const f32x4*)(pxA + (size_t)t * kI + k);
      f32x4 xb = *(const f32x4*)(pxA + (size_t)t * kI + k + 4);
      f32x4 ya = *(const f32x4*)(pxB + (size_t)t * kI + k);
      f32x4 yb = *(const f32x4*)(pxB + (size_t)t * kI + k + 4);
      short8 b0, b1;
#pragma unroll
      for (int jj = 0; jj < 4; ++jj) {
        b0[jj] = (short)f2bf(xa[jj]); b0[jj + 4] = (short)f2bf(xb[jj]);
        b1[jj] = (short)f2bf(ya[jj]); b1[jj + 4] = (short)f2bf(yb[jj]);
      }
      acc0 = MFMA16(wx[kt], b0, acc0);
      acc1 = MFMA16(wx[kt], b1, acc1);
    }

    // ---- wait for h_t: only wave 0 polls (validated LLC flag protocol)
    if (t > 0 && wv == 0) {
      while (!__all((int)(ld_flag(&gflags[lane & 31]) >= (unsigned)t)))
        __builtin_amdgcn_s_sleep(2);
      asm volatile("" ::: "memory");
    }
    __syncthreads();

    // ---- cooperative stage: h[32 x 2048] -> LDS via global_load_lds DMA.
    // 16 wave-instrs x 1KB each; pre-swizzled global src, linear LDS dest.
#pragma unroll
    for (int j = 0; j < 16; ++j) {
      const int g = wv * 16 + j;
      const int row = g >> 2;
      const int q = (g & 3) * 1024;
      const char* gp = (const char*)hc + (size_t)(r0 + row) * 4096 + q +
                       (laneoff ^ ((row & 7) << 4));
      gload_lds16(gp, smem + row * 4096 + q);
    }
    __syncthreads();  // drains vmcnt(0): all DMA landed in LDS

    // ---- h_t @ Whh: A from VGPR, B from swizzled LDS
#pragma unroll
    for (int kt = 0; kt < 32; ++kt) {
      const int kb = (kh * 1024 + kt * 32 + klo) * 2;
      short8 hb0 = *(const short8*)(smem + swz(brow, kb));
      short8 hb1 = *(const short8*)(smem + swz(brow + 16, kb));
      acc0 = MFMA16(wa[kt], hb0, acc0);
      acc1 = MFMA16(wa[kt], hb1, acc1);
    }

    // ---- K-half handoff (non-atomic zone; one owner per slot)
    if (kh == 1) {
      *zslot(smem, brow, ci * 4 + nq) = acc0;
      *zslot(smem, brow + 16, ci * 4 + nq) = acc1;
    }
    __syncthreads();

    // ---- kh==0: combine halves, tanh, pack 4 bf16 -> one 8B LLC store per tile
    if (kh == 0) {
      f32x4 s0 = *zslot(smem, brow, ci * 4 + nq);
      f32x4 s1 = *zslot(smem, brow + 16, ci * 4 + nq);
      u64 v0 = 0, v1 = 0;
#pragma unroll
      for (int jj = 0; jj < 4; ++jj) {
        v0 |= (u64)f2bf(fast_tanh(acc0[jj] + s0[jj] + bh[jj])) << (16 * jj);
        v1 |= (u64)f2bf(fast_tanh(acc1[jj] + s1[jj] + bh[jj])) << (16 * jj);
      }
      const int qoff = (n0 >> 2) + ci * 4 + nq;
      st_h8(hn + (size_t)(r0 + brow) * 512 + qoff, v0);
      st_h8(hn + (size_t)(r0 + 16 + brow) * 512 + qoff, v1);
    }

    // ---- release: __syncthreads drains each wave's vmcnt (stores ack'd at LLC)
    __syncthreads();
    if (tid == 0) st_flag(&gflags[cg], (unsigned)(t + 1));
  }

  // ================= epilogue: out = h_final @ Wph + Bp =================
  if (wv == 0) {
    while (!__all((int)(ld_flag(&gflags[lane & 31]) >= (unsigned)kS)))
      __builtin_amdgcn_s_sleep(2);
    asm volatile("" ::: "memory");
  }
  __syncthreads();

  // stage Wph^T slice [32 cls-cols][2048 k] into h-stage region
  {
    const int c = tid & 31;
    const int kk = tid >> 5;  // 16 k-stripes
    for (int k = kk; k < kH; k += 16)
      *(unsigned short*)(smem + swz(c, k * 2)) = f2bf(Wph[(size_t)k * kC + cg * 32 + c]);
  }
  __syncthreads();

  // waves 0..3 active: (ci2 = wv&1 -> 16 cls-cols, kh2 = wv>>1 -> K-half)
  const bool act = (wv < 4);
  const int ci2 = wv & 1;
  const int kh2 = (wv >> 1) & 1;
  f32x4 oacc0 = {0.f, 0.f, 0.f, 0.f};
  f32x4 oacc1 = {0.f, 0.f, 0.f, 0.f};
  if (act) {
    const u64* phA = h0buf + (size_t)(r0 + brow) * 512;   // h_final (t=511 -> h0)
    const u64* phB = h0buf + (size_t)(r0 + 16 + brow) * 512;
#pragma unroll 8
    for (int kt = 0; kt < 32; ++kt) {
      const int gk = kh2 * 1024 + kt * 32 + klo;
      short8 a = *(const short8*)(smem + swz(ci2 * 16 + brow, gk * 2));
      union { u64 q[2]; short8 s; } uA, uB;
      uA.q[0] = ld_h8(phA + (gk >> 2)); uA.q[1] = ld_h8(phA + (gk >> 2) + 1);
      uB.q[0] = ld_h8(phB + (gk >> 2)); uB.q[1] = ld_h8(phB + (gk >> 2) + 1);
      oacc0 = MFMA16(a, uA.s, oacc0);
      oacc1 = MFMA16(a, uB.s, oacc1);
    }
  }
  if (act && kh2 == 1) {
    *zslot2(smem, brow, ci2 * 4 + nq) = oacc0;
    *zslot2(smem, brow + 16, ci2 * 4 + nq) = oacc1;
  }
  __syncthreads();
  if (act && kh2 == 0) {
    f32x4 s0 = *zslot2(smem, brow, ci2 * 4 + nq);
    f32x4 s1 = *zslot2(smem, brow + 16, ci2 * 4 + nq);
    const int ocol = cg * 32 + ci2 * 16 + nq * 4;
    const f32x4 bp = *(const f32x4*)(Bp + ocol);
#pragma unroll
    for (int jj = 0; jj < 4; ++jj) {
      out[(size_t)(r0 + brow) * kC + ocol + jj] = oacc0[jj] + s0[jj] + bp[jj];
      out[(size_t)(r0 + 16 + brow) * kC + ocol + jj] = oacc1[jj] + s1[jj] + bp[jj];
    }
  }
}

extern "C" void kernel_launch(void* const* d_in, const int* in_sizes, int n_in,
                              void* d_out, int out_size, void* d_ws, size_t ws_size,
                              hipStream_t stream) {
  const float* x   = (const float*)d_in[0];
  const float* Whx = (const float*)d_in[1];
  const float* Whh = (const float*)d_in[2];
  const float* Wph = (const float*)d_in[3];
  const float* Bh  = (const float*)d_in[4];
  const float* Bp  = (const float*)d_in[5];
  float* out = (float*)d_out;

  char* ws = (char*)d_ws;
  u64* h0         = (u64*)(ws);                   // 1 MB: h ping
  u64* h1         = (u64*)(ws + (1 << 20));       // 1 MB: h pong
  unsigned* flags = (unsigned*)(ws + (2 << 20));  // 8 groups x 32 step flags

  hipMemsetAsync(h0, 0, (size_t)kBt * kH * sizeof(unsigned short), stream);  // h_0 = 0
  hipMemsetAsync(flags, 0, 4096, stream);                                    // reset barrier

  dim3 grid(256), block(512);
  size_t lds = 139264;  // 128K h-stage + 8K zone
  hipLaunchKernelGGL(rnn_fused, grid, block, lds, stream,
                     x, Whx, Whh, Wph, Bh, Bp, out, h0, h1, flags);
}

// Round 12
// 3897.681 us; speedup vs baseline: 1.4132x; 1.0538x over previous
//
#include <hip/hip_runtime.h>
#include <hip/hip_bf16.h>

typedef __attribute__((ext_vector_type(8))) short short8;
typedef __attribute__((ext_vector_type(4))) float f32x4;
typedef unsigned long long u64;

#define MFMA16(A, B, C) __builtin_amdgcn_mfma_f32_16x16x32_bf16((A), (B), (C), 0, 0, 0)

static constexpr int kS = 512;   // seq
static constexpr int kI = 256;   // in_dim
static constexpr int kH = 2048;  // hidden
static constexpr int kC = 1024;  // classes
static constexpr int kBt = 256;  // batch

// WG tile: 32 batch rows x 64 hidden cols. Grid 256 = 8 rowgroups x 32 colgroups.
// R11 trunk (4107us) + intra-step software pipeline:
//   stage DMA issued {Q0,Q2} then {Q1,Q3}; vmcnt(8)+raw s_barrier -> MFMA half1
//   overlaps Q1/Q3 flight; vmcnt(0)+raw s_barrier -> MFMA half2.
// Balanced epilogue: kh1 publishes row-tile0 partials, kh0 publishes tile1;
// each group combines+stores its own tile (no idle wave group).
// Cross-WG sync: LLC agent-scope intrinsics only (validated R2-R11).
// LDS map (dynamic, 139264 B):
//   [0,      131072): h-stage [32 rows][2048 k] bf16, stride 4096 B, XOR swizzle
//                     (epilogue reuse: Wph^T [32 cls-cols][2048 k])
//   [131072, 139264): K-half zone [32 rows][16 quads f32x4], XOR swizzle
static constexpr int ZONE_OFF = 131072;

__device__ __forceinline__ int swz(int row, int kbyte) {
  return row * 4096 + (kbyte ^ ((row & 7) << 4));
}
__device__ __forceinline__ f32x4* zslot(char* smem, int row, int quad) {
  return (f32x4*)(smem + ZONE_OFF + row * 256 + (((quad ^ row) & 15) << 4));
}
__device__ __forceinline__ f32x4* zslot2(char* smem, int row, int quad) {  // epilogue
  return (f32x4*)(smem + ZONE_OFF + row * 128 + (((quad ^ row) & 7) << 4));
}

__device__ __forceinline__ unsigned short f2bf(float f) {  // RNE fp32->bf16
  unsigned u = __float_as_uint(f);
  u += 0x7fffu + ((u >> 16) & 1u);
  return (unsigned short)(u >> 16);
}

__device__ __forceinline__ float fast_tanh(float v) {
  float a = __builtin_fabsf(v);
  float e = __expf(-2.0f * a);
  float r = (1.0f - e) / (1.0f + e);
  return __builtin_copysignf(r, v);
}

// Validated LLC-coherent intrinsic path (rounds 2-5, 7, 11).
__device__ __forceinline__ u64 ld_h8(const u64* p) {
  return __hip_atomic_load(p, __ATOMIC_RELAXED, __HIP_MEMORY_SCOPE_AGENT);
}
__device__ __forceinline__ void st_h8(u64* p, u64 v) {
  __hip_atomic_store(p, v, __ATOMIC_RELAXED, __HIP_MEMORY_SCOPE_AGENT);
}
__device__ __forceinline__ unsigned ld_flag(const unsigned* p) {
  return __hip_atomic_load(p, __ATOMIC_RELAXED, __HIP_MEMORY_SCOPE_AGENT);
}
__device__ __forceinline__ void st_flag(unsigned* p, unsigned v) {
  __hip_atomic_store(p, v, __ATOMIC_RELAXED, __HIP_MEMORY_SCOPE_AGENT);
}

// Direct global->LDS DMA, 16B/lane, CPol aux=17 = SC0|SC1 (LLC coherence
// point). LDS dest = wave-uniform base + lane*16; per-lane GLOBAL address
// carries the XOR swizzle (m173 pattern). Validated R11.
__device__ __forceinline__ void gload_lds16(const void* g, void* l) {
  __builtin_amdgcn_global_load_lds(
      (const __attribute__((address_space(1))) void*)g,
      (__attribute__((address_space(3))) void*)l, 16, 0, 17);
}

__global__ __launch_bounds__(512, 2)
void rnn_fused(const float* __restrict__ x, const float* __restrict__ Whx,
               const float* __restrict__ Whh, const float* __restrict__ Wph,
               const float* __restrict__ Bh, const float* __restrict__ Bp,
               float* __restrict__ out,
               u64* __restrict__ h0buf, u64* __restrict__ h1buf,
               unsigned* __restrict__ flags) {
  extern __shared__ char smem[];
  const int tid = (int)threadIdx.x;
  const int lane = tid & 63;
  const int wv = tid >> 6;       // 0..7
  const int ci = wv & 3;         // 16-col group within WG
  const int kh = wv >> 2;        // K-half (0/1)
  const int wg = (int)blockIdx.x;
  const int rg = wg >> 5;        // 0..7  : rowgroup (32 rows, barrier domain)
  const int cg = wg & 31;        // 0..31 : colgroup (64 hidden cols)
  const int r0 = rg * 32;
  const int n0 = cg * 64;

  const int brow = lane & 15;    // batch row within 16-row tile; also A-row
  const int nq = lane >> 4;      // k-segment / D col-quad
  const int klo = nq * 8;
  const int wcol = n0 + ci * 16 + brow;   // this lane's hidden col (A operand)

  // ---- persistent A fragments in VGPRs (one-time gather, cached path)
  short8 wa[32];  // Whh^T: 16 cols x 1024 k (this wave's K-half)
#pragma unroll
  for (int kt = 0; kt < 32; ++kt) {
    const float* wp = Whh + (size_t)(kh * 1024 + kt * 32 + klo) * kH + wcol;
#pragma unroll
    for (int jj = 0; jj < 8; ++jj) wa[kt][jj] = (short)f2bf(wp[(size_t)jj * kH]);
  }
  short8 wx[4];   // Whx^T: 16 cols x 128 k (K-half of 256)
#pragma unroll
  for (int kt = 0; kt < 4; ++kt) {
    const float* wp = Whx + (size_t)(kh * 128 + kt * 32 + klo) * kH + wcol;
#pragma unroll
    for (int jj = 0; jj < 8; ++jj) wx[kt][jj] = (short)f2bf(wp[(size_t)jj * kH]);
  }

  const f32x4 bh = *(const f32x4*)(Bh + n0 + ci * 16 + nq * 4);

  // staging: wave wv owns rows [4wv, 4wv+4); 16 DMA instrs ordered
  // {Q0 rows, Q2 rows, Q1 rows, Q3 rows}; lane gbyte pre-swizzled.
  const int laneoff = lane * 16;

  unsigned* gflags = flags + (rg << 5);  // 32 flags per rowgroup
  const float* pxA = x + (size_t)(r0 + brow) * (kS * kI);
  const float* pxB = x + (size_t)(r0 + 16 + brow) * (kS * kI);

  for (int t = 0; t < kS; ++t) {
    const u64* hc = (t & 1) ? h1buf : h0buf;
    u64* hn       = (t & 1) ? h0buf : h1buf;
    f32x4 acc0 = {0.f, 0.f, 0.f, 0.f};
    f32x4 acc1 = {0.f, 0.f, 0.f, 0.f};

    // ---- x_t @ Whx over this wave's K-half (no h dep: overlaps flag wait)
#pragma unroll
    for (int kt = 0; kt < 4; ++kt) {
      const int k = kh * 128 + kt * 32 + klo;
      f32x4 xa = *(const f32x4*)(pxA + (size_t)t * kI + k);
      f32x4 xb = *(const f32x4*)(pxA + (size_t)t * kI + k + 4);
      f32x4 ya = *(const f32x4*)(pxB + (size_t)t * kI + k);
      f32x4 yb = *(const f32x4*)(pxB + (size_t)t * kI + k + 4);
      short8 b0, b1;
#pragma unroll
      for (int jj = 0; jj < 4; ++jj) {
        b0[jj] = (short)f2bf(xa[jj]); b0[jj + 4] = (short)f2bf(xb[jj]);
        b1[jj] = (short)f2bf(ya[jj]); b1[jj + 4] = (short)f2bf(yb[jj]);
      }
      acc0 = MFMA16(wx[kt], b0, acc0);
      acc1 = MFMA16(wx[kt], b1, acc1);
    }

    // ---- wait for h_t: only wave 0 polls (validated LLC flag protocol)
    if (t > 0 && wv == 0) {
      while (!__all((int)(ld_flag(&gflags[lane & 31]) >= (unsigned)t)))
        __builtin_amdgcn_s_sleep(2);
      asm volatile("" ::: "memory");
    }
    __syncthreads();

    // ---- pipelined stage: issue all 16 DMA, consume in 2 halves.
    // order: Q0(kh0 half1), Q2(kh1 half1), Q1, Q3.
#pragma unroll
    for (int jj = 0; jj < 16; ++jj) {
      const int qsel = jj >> 2;  // 0..3 -> quarter 0,2,1,3
      const int q = (qsel == 0) ? 0 : (qsel == 1) ? 2 : (qsel == 2) ? 1 : 3;
      const int row = 4 * wv + (jj & 3);
      const char* gp = (const char*)hc + (size_t)(r0 + row) * 4096 + q * 1024 +
                       (laneoff ^ ((row & 7) << 4));
      gload_lds16(gp, smem + row * 4096 + q * 1024);
    }
    asm volatile("s_waitcnt vmcnt(8)" ::: "memory");   // own Q0+Q2 done
    __builtin_amdgcn_sched_barrier(0);
    __builtin_amdgcn_s_barrier();                      // all waves' Q0+Q2 done
    __builtin_amdgcn_sched_barrier(0);

    // ---- MFMA half 1 (first 1KB of this wave's K-half; Q1/Q3 in flight)
#pragma unroll
    for (int kt = 0; kt < 16; ++kt) {
      const int kb = (kh * 1024 + kt * 32 + klo) * 2;
      short8 hb0 = *(const short8*)(smem + swz(brow, kb));
      short8 hb1 = *(const short8*)(smem + swz(brow + 16, kb));
      acc0 = MFMA16(wa[kt], hb0, acc0);
      acc1 = MFMA16(wa[kt], hb1, acc1);
    }
    asm volatile("s_waitcnt vmcnt(0)" ::: "memory");   // own Q1+Q3 done
    __builtin_amdgcn_sched_barrier(0);
    __builtin_amdgcn_s_barrier();                      // all waves' Q1+Q3 done
    __builtin_amdgcn_sched_barrier(0);

    // ---- MFMA half 2
#pragma unroll
    for (int kt = 16; kt < 32; ++kt) {
      const int kb = (kh * 1024 + kt * 32 + klo) * 2;
      short8 hb0 = *(const short8*)(smem + swz(brow, kb));
      short8 hb1 = *(const short8*)(smem + swz(brow + 16, kb));
      acc0 = MFMA16(wa[kt], hb0, acc0);
      acc1 = MFMA16(wa[kt], hb1, acc1);
    }

    // ---- balanced K-half handoff: kh1 publishes row-tile0, kh0 row-tile1
    if (kh == 1) {
      *zslot(smem, brow, ci * 4 + nq) = acc0;          // rows 0-15 partial
    } else {
      *zslot(smem, brow + 16, ci * 4 + nq) = acc1;     // rows 16-31 partial
    }
    __syncthreads();

    // ---- combine+tanh+store: kh0 owns row-tile0, kh1 owns row-tile1
    {
      const int qoff = (n0 >> 2) + ci * 4 + nq;
      if (kh == 0) {
        f32x4 s0 = *zslot(smem, brow, ci * 4 + nq);
        u64 v0 = 0;
#pragma unroll
        for (int jj = 0; jj < 4; ++jj)
          v0 |= (u64)f2bf(fast_tanh(acc0[jj] + s0[jj] + bh[jj])) << (16 * jj);
        st_h8(hn + (size_t)(r0 + brow) * 512 + qoff, v0);
      } else {
        f32x4 s1 = *zslot(smem, brow + 16, ci * 4 + nq);
        u64 v1 = 0;
#pragma unroll
        for (int jj = 0; jj < 4; ++jj)
          v1 |= (u64)f2bf(fast_tanh(acc1[jj] + s1[jj] + bh[jj])) << (16 * jj);
        st_h8(hn + (size_t)(r0 + 16 + brow) * 512 + qoff, v1);
      }
    }

    // ---- release: __syncthreads drains each wave's vmcnt (stores ack'd at LLC)
    __syncthreads();
    if (tid == 0) st_flag(&gflags[cg], (unsigned)(t + 1));
  }

  // ================= epilogue: out = h_final @ Wph + Bp =================
  if (wv == 0) {
    while (!__all((int)(ld_flag(&gflags[lane & 31]) >= (unsigned)kS)))
      __builtin_amdgcn_s_sleep(2);
    asm volatile("" ::: "memory");
  }
  __syncthreads();

  // stage Wph^T slice [32 cls-cols][2048 k] into h-stage region
  {
    const int c = tid & 31;
    const int kk = tid >> 5;  // 16 k-stripes
    for (int k = kk; k < kH; k += 16)
      *(unsigned short*)(smem + swz(c, k * 2)) = f2bf(Wph[(size_t)k * kC + cg * 32 + c]);
  }
  __syncthreads();

  // waves 0..3 active: (ci2 = wv&1 -> 16 cls-cols, kh2 = wv>>1 -> K-half)
  const bool act = (wv < 4);
  const int ci2 = wv & 1;
  const int kh2 = (wv >> 1) & 1;
  f32x4 oacc0 = {0.f, 0.f, 0.f, 0.f};
  f32x4 oacc1 = {0.f, 0.f, 0.f, 0.f};
  if (act) {
    const u64* phA = h0buf + (size_t)(r0 + brow) * 512;   // h_final (t=511 -> h0)
    const u64* phB = h0buf + (size_t)(r0 + 16 + brow) * 512;
#pragma unroll 8
    for (int kt = 0; kt < 32; ++kt) {
      const int gk = kh2 * 1024 + kt * 32 + klo;
      short8 a = *(const short8*)(smem + swz(ci2 * 16 + brow, gk * 2));
      union { u64 q[2]; short8 s; } uA, uB;
      uA.q[0] = ld_h8(phA + (gk >> 2)); uA.q[1] = ld_h8(phA + (gk >> 2) + 1);
      uB.q[0] = ld_h8(phB + (gk >> 2)); uB.q[1] = ld_h8(phB + (gk >> 2) + 1);
      oacc0 = MFMA16(a, uA.s, oacc0);
      oacc1 = MFMA16(a, uB.s, oacc1);
    }
  }
  if (act && kh2 == 1) {
    *zslot2(smem, brow, ci2 * 4 + nq) = oacc0;
    *zslot2(smem, brow + 16, ci2 * 4 + nq) = oacc1;
  }
  __syncthreads();
  if (act && kh2 == 0) {
    f32x4 s0 = *zslot2(smem, brow, ci2 * 4 + nq);
    f32x4 s1 = *zslot2(smem, brow + 16, ci2 * 4 + nq);
    const int ocol = cg * 32 + ci2 * 16 + nq * 4;
    const f32x4 bp = *(const f32x4*)(Bp + ocol);
#pragma unroll
    for (int jj = 0; jj < 4; ++jj) {
      out[(size_t)(r0 + brow) * kC + ocol + jj] = oacc0[jj] + s0[jj] + bp[jj];
      out[(size_t)(r0 + 16 + brow) * kC + ocol + jj] = oacc1[jj] + s1[jj] + bp[jj];
    }
  }
}

extern "C" void kernel_launch(void* const* d_in, const int* in_sizes, int n_in,
                              void* d_out, int out_size, void* d_ws, size_t ws_size,
                              hipStream_t stream) {
  const float* x   = (const float*)d_in[0];
  const float* Whx = (const float*)d_in[1];
  const float* Whh = (const float*)d_in[2];
  const float* Wph = (const float*)d_in[3];
  const float* Bh  = (const float*)d_in[4];
  const float* Bp  = (const float*)d_in[5];
  float* out = (float*)d_out;

  char* ws = (char*)d_ws;
  u64* h0         = (u64*)(ws);                   // 1 MB: h ping
  u64* h1         = (u64*)(ws + (1 << 20));       // 1 MB: h pong
  unsigned* flags = (unsigned*)(ws + (2 << 20));  // 8 groups x 32 step flags

  hipMemsetAsync(h0, 0, (size_t)kBt * kH * sizeof(unsigned short), stream);  // h_0 = 0
  hipMemsetAsync(flags, 0, 4096, stream);                                    // reset barrier

  dim3 grid(256), block(512);
  size_t lds = 139264;  // 128K h-stage + 8K zone
  hipLaunchKernelGGL(rnn_fused, grid, block, lds, stream,
                     x, Whx, Whh, Wph, Bh, Bp, out, h0, h1, flags);
}

// Round 13
// 3488.610 us; speedup vs baseline: 1.5789x; 1.1173x over previous
//
#include <hip/hip_runtime.h>
#include <hip/hip_bf16.h>

typedef __attribute__((ext_vector_type(8))) short short8;
typedef __attribute__((ext_vector_type(4))) float f32x4;
typedef __attribute__((ext_vector_type(16))) float f32x16;
typedef unsigned long long u64;

#define MFMA16(A, B, C) __builtin_amdgcn_mfma_f32_16x16x32_bf16((A), (B), (C), 0, 0, 0)
#define MFMA32(A, B, C) __builtin_amdgcn_mfma_f32_32x32x16_bf16((A), (B), (C), 0, 0, 0)

static constexpr int kS = 512;   // seq
static constexpr int kI = 256;   // in_dim
static constexpr int kH = 2048;  // hidden
static constexpr int kC = 1024;  // classes
static constexpr int kBt = 256;  // batch

// WG tile: 32 batch rows x 64 hidden cols. Grid 256 = 8 rowgroups x 32 colgroups.
// R12 trunk (3898us) with the recurrence GEMM moved to mfma_32x32x16 (mapping
// HW-validated in R3): waves = ci2{0,1} x kq{0..3}. Each wave: 32 hidden cols,
// 512-wide K-quarter, wa[32] A-frags in VGPR (128 regs; free headroom since
// LDS caps the CU at 8 waves which is legal up to 256 VGPR). Halves
// ds_read_b128 count and MFMA count. 4-way K-combine: wave kq publishes acc
// quads q'!=kq to zone, combines own quad (balanced, atomic-free).
// DMA pipeline: issue {Q0,Q1},{Q2,Q3}; vmcnt(8)+s_barrier -> kq<2 compute;
// vmcnt(0)+s_barrier -> kq>=2. Cross-WG sync: LLC agent-scope only (R2-R12).
// LDS map (dynamic, 155648 B):
//   [0,      131072): h-stage [32 rows][2048 k] bf16, stride 4096 B, XOR swizzle
//                     (epilogue reuse: Wph^T [32 cls-cols][2048 k])
//   [131072, 155648): K-combine zone [ci2][quad][slot0..2][lane] f32x4 = 24KB
static constexpr int ZONE_OFF = 131072;

__device__ __forceinline__ int swz(int row, int kbyte) {
  return row * 4096 + (kbyte ^ ((row & 7) << 4));
}
__device__ __forceinline__ f32x4* zq(char* smem, int ci2, int quad, int slot, int lane) {
  return (f32x4*)(smem + ZONE_OFF + ((((ci2 * 4 + quad) * 3 + slot) * 64 + lane) << 4));
}
__device__ __forceinline__ f32x4* zslot2(char* smem, int row, int quad) {  // final proj
  return (f32x4*)(smem + ZONE_OFF + row * 128 + (((quad ^ row) & 7) << 4));
}

__device__ __forceinline__ unsigned short f2bf(float f) {  // RNE fp32->bf16
  unsigned u = __float_as_uint(f);
  u += 0x7fffu + ((u >> 16) & 1u);
  return (unsigned short)(u >> 16);
}

__device__ __forceinline__ float fast_tanh(float v) {
  float a = __builtin_fabsf(v);
  float e = __expf(-2.0f * a);
  float r = (1.0f - e) / (1.0f + e);
  return __builtin_copysignf(r, v);
}

// Validated LLC-coherent intrinsic path (rounds 2-5, 7, 11, 12).
__device__ __forceinline__ u64 ld_h8(const u64* p) {
  return __hip_atomic_load(p, __ATOMIC_RELAXED, __HIP_MEMORY_SCOPE_AGENT);
}
__device__ __forceinline__ void st_h8(u64* p, u64 v) {
  __hip_atomic_store(p, v, __ATOMIC_RELAXED, __HIP_MEMORY_SCOPE_AGENT);
}
__device__ __forceinline__ unsigned ld_flag(const unsigned* p) {
  return __hip_atomic_load(p, __ATOMIC_RELAXED, __HIP_MEMORY_SCOPE_AGENT);
}
__device__ __forceinline__ void st_flag(unsigned* p, unsigned v) {
  __hip_atomic_store(p, v, __ATOMIC_RELAXED, __HIP_MEMORY_SCOPE_AGENT);
}

// Direct global->LDS DMA, 16B/lane, aux=17 (SC0|SC1). Validated R11/R12.
__device__ __forceinline__ void gload_lds16(const void* g, void* l) {
  __builtin_amdgcn_global_load_lds(
      (const __attribute__((address_space(1))) void*)g,
      (__attribute__((address_space(3))) void*)l, 16, 0, 17);
}

__global__ __launch_bounds__(512, 2)
void rnn_fused(const float* __restrict__ x, const float* __restrict__ Whx,
               const float* __restrict__ Whh, const float* __restrict__ Wph,
               const float* __restrict__ Bh, const float* __restrict__ Bp,
               float* __restrict__ out,
               u64* __restrict__ h0buf, u64* __restrict__ h1buf,
               unsigned* __restrict__ flags) {
  extern __shared__ char smem[];
  const int tid = (int)threadIdx.x;
  const int lane = tid & 63;
  const int wv = tid >> 6;       // 0..7
  const int ci2 = wv & 1;        // 32-col half
  const int kq = wv >> 1;        // K-quarter 0..3 (512 k each)
  const int wg = (int)blockIdx.x;
  const int rg = wg >> 5;        // 0..7  : rowgroup (32 rows, barrier domain)
  const int cg = wg & 31;        // 0..31 : colgroup (64 hidden cols)
  const int r0 = rg * 32;
  const int n0 = cg * 64;

  // 32x32x16 lane roles (R3-validated mapping)
  const int j32 = lane & 31;     // A row (hidden col) == B col (batch row)
  const int hi = lane >> 5;      // k-subgroup / D row-quad half
  const int wcol2 = n0 + ci2 * 32 + j32;  // this lane's hidden col (A operand)

  // ---- persistent A fragments in VGPRs (one-time gather, cached path)
  short8 wa[32];  // Whh^T: 32 cols x 512 k (this wave's K-quarter)
#pragma unroll
  for (int ks = 0; ks < 32; ++ks) {
    const float* wp = Whh + (size_t)(kq * 512 + ks * 16 + hi * 8) * kH + wcol2;
#pragma unroll
    for (int jj = 0; jj < 8; ++jj) wa[ks][jj] = (short)f2bf(wp[(size_t)jj * kH]);
  }
  short8 wx[4];   // Whx^T: 32 cols x 64 k (K-quarter of 256)
#pragma unroll
  for (int ks = 0; ks < 4; ++ks) {
    const float* wp = Whx + (size_t)(kq * 64 + ks * 16 + hi * 8) * kH + wcol2;
#pragma unroll
    for (int jj = 0; jj < 8; ++jj) wx[ks][jj] = (short)f2bf(wp[(size_t)jj * kH]);
  }

  // bias for this lane's owned quad (cols 8*kq + 4*hi + 0..3 within ci2 half)
  const f32x4 bh = *(const f32x4*)(Bh + n0 + ci2 * 32 + 8 * kq + 4 * hi);

  const int laneoff = lane * 16;
  unsigned* gflags = flags + (rg << 5);  // 32 flags per rowgroup
  const float* px_row = x + (size_t)(r0 + j32) * (kS * kI);

  for (int t = 0; t < kS; ++t) {
    const u64* hc = (t & 1) ? h1buf : h0buf;
    u64* hn       = (t & 1) ? h0buf : h1buf;
    f32x16 acc = {0.f,0.f,0.f,0.f,0.f,0.f,0.f,0.f,0.f,0.f,0.f,0.f,0.f,0.f,0.f,0.f};

    // ---- x_t @ Whx over this wave's x K-quarter (overlaps flag wait)
#pragma unroll
    for (int ks = 0; ks < 4; ++ks) {
      const int k = kq * 64 + ks * 16 + hi * 8;
      f32x4 xa = *(const f32x4*)(px_row + (size_t)t * kI + k);
      f32x4 xb = *(const f32x4*)(px_row + (size_t)t * kI + k + 4);
      short8 bx;
#pragma unroll
      for (int jj = 0; jj < 4; ++jj) {
        bx[jj] = (short)f2bf(xa[jj]); bx[jj + 4] = (short)f2bf(xb[jj]);
      }
      acc = MFMA32(wx[ks], bx, acc);
    }

    // ---- wait for h_t: only wave 0 polls (validated LLC flag protocol)
    if (t > 0 && wv == 0) {
      while (!__all((int)(ld_flag(&gflags[lane & 31]) >= (unsigned)t)))
        __builtin_amdgcn_s_sleep(2);
      asm volatile("" ::: "memory");
    }
    __syncthreads();

    // ---- pipelined stage: issue 16 DMA in quarter order Q0,Q1,Q2,Q3
#pragma unroll
    for (int jj = 0; jj < 16; ++jj) {
      const int q = jj >> 2;
      const int row = 4 * wv + (jj & 3);
      const char* gp = (const char*)hc + (size_t)(r0 + row) * 4096 + q * 1024 +
                       (laneoff ^ ((row & 7) << 4));
      gload_lds16(gp, smem + row * 4096 + q * 1024);
    }
    asm volatile("s_waitcnt vmcnt(8)" ::: "memory");   // own Q0+Q1 done
    __builtin_amdgcn_sched_barrier(0);
    __builtin_amdgcn_s_barrier();                      // all waves' Q0+Q1 done
    __builtin_amdgcn_sched_barrier(0);

    // ---- kq<2 compute (quarter kq resident; Q2/Q3 still in flight)
    if (kq < 2) {
#pragma unroll
      for (int ks = 0; ks < 32; ++ks) {
        const int kb = kq * 1024 + ks * 32 + hi * 16;
        short8 hb = *(const short8*)(smem + swz(j32, kb));
        acc = MFMA32(wa[ks], hb, acc);
      }
#pragma unroll
      for (int qp = 0; qp < 4; ++qp) {
        if (qp != kq) {
          f32x4 part = {acc[4 * qp], acc[4 * qp + 1], acc[4 * qp + 2], acc[4 * qp + 3]};
          *zq(smem, ci2, qp, kq - (kq > qp ? 1 : 0), lane) = part;
        }
      }
    }
    asm volatile("s_waitcnt vmcnt(0)" ::: "memory");   // own Q2+Q3 done
    __builtin_amdgcn_sched_barrier(0);
    __builtin_amdgcn_s_barrier();                      // all waves' Q2+Q3 done
    __builtin_amdgcn_sched_barrier(0);

    // ---- kq>=2 compute
    if (kq >= 2) {
#pragma unroll
      for (int ks = 0; ks < 32; ++ks) {
        const int kb = kq * 1024 + ks * 32 + hi * 16;
        short8 hb = *(const short8*)(smem + swz(j32, kb));
        acc = MFMA32(wa[ks], hb, acc);
      }
#pragma unroll
      for (int qp = 0; qp < 4; ++qp) {
        if (qp != kq) {
          f32x4 part = {acc[4 * qp], acc[4 * qp + 1], acc[4 * qp + 2], acc[4 * qp + 3]};
          *zq(smem, ci2, qp, kq - (kq > qp ? 1 : 0), lane) = part;
        }
      }
    }
    __syncthreads();  // all partials published

    // ---- combine own quad kq: 3 zone reads + own regs, tanh, pack, store
    {
      f32x4 s0 = *zq(smem, ci2, kq, 0, lane);
      f32x4 s1 = *zq(smem, ci2, kq, 1, lane);
      f32x4 s2 = *zq(smem, ci2, kq, 2, lane);
      u64 v = 0;
#pragma unroll
      for (int jj = 0; jj < 4; ++jj) {
        float sum = acc[4 * kq + jj] + s0[jj] + s1[jj] + s2[jj] + bh[jj];
        v |= (u64)f2bf(fast_tanh(sum)) << (16 * jj);
      }
      const int qoff = (n0 + ci2 * 32 + 8 * kq + 4 * hi) >> 2;
      st_h8(hn + (size_t)(r0 + j32) * 512 + qoff, v);
    }

    // ---- release: __syncthreads drains each wave's vmcnt (stores ack'd at LLC)
    __syncthreads();
    if (tid == 0) st_flag(&gflags[cg], (unsigned)(t + 1));
  }

  // ======== epilogue: out = h_final @ Wph + Bp (byte-identical to R12) ========
  if (wv == 0) {
    while (!__all((int)(ld_flag(&gflags[lane & 31]) >= (unsigned)kS)))
      __builtin_amdgcn_s_sleep(2);
    asm volatile("" ::: "memory");
  }
  __syncthreads();

  {
    const int c = tid & 31;
    const int kk = tid >> 5;  // 16 k-stripes
    for (int k = kk; k < kH; k += 16)
      *(unsigned short*)(smem + swz(c, k * 2)) = f2bf(Wph[(size_t)k * kC + cg * 32 + c]);
  }
  __syncthreads();

  const int brow = lane & 15;
  const int nq = lane >> 4;
  const int klo = nq * 8;
  const bool act = (wv < 4);
  const int ci16 = wv & 1;
  const int kh2 = (wv >> 1) & 1;
  f32x4 oacc0 = {0.f, 0.f, 0.f, 0.f};
  f32x4 oacc1 = {0.f, 0.f, 0.f, 0.f};
  if (act) {
    const u64* phA = h0buf + (size_t)(r0 + brow) * 512;   // h_final (t=511 -> h0)
    const u64* phB = h0buf + (size_t)(r0 + 16 + brow) * 512;
#pragma unroll 8
    for (int kt = 0; kt < 32; ++kt) {
      const int gk = kh2 * 1024 + kt * 32 + klo;
      short8 a = *(const short8*)(smem + swz(ci16 * 16 + brow, gk * 2));
      union { u64 q[2]; short8 s; } uA, uB;
      uA.q[0] = ld_h8(phA + (gk >> 2)); uA.q[1] = ld_h8(phA + (gk >> 2) + 1);
      uB.q[0] = ld_h8(phB + (gk >> 2)); uB.q[1] = ld_h8(phB + (gk >> 2) + 1);
      oacc0 = MFMA16(a, uA.s, oacc0);
      oacc1 = MFMA16(a, uB.s, oacc1);
    }
  }
  if (act && kh2 == 1) {
    *zslot2(smem, brow, ci16 * 4 + nq) = oacc0;
    *zslot2(smem, brow + 16, ci16 * 4 + nq) = oacc1;
  }
  __syncthreads();
  if (act && kh2 == 0) {
    f32x4 s0 = *zslot2(smem, brow, ci16 * 4 + nq);
    f32x4 s1 = *zslot2(smem, brow + 16, ci16 * 4 + nq);
    const int ocol = cg * 32 + ci16 * 16 + nq * 4;
    const f32x4 bp = *(const f32x4*)(Bp + ocol);
#pragma unroll
    for (int jj = 0; jj < 4; ++jj) {
      out[(size_t)(r0 + brow) * kC + ocol + jj] = oacc0[jj] + s0[jj] + bp[jj];
      out[(size_t)(r0 + 16 + brow) * kC + ocol + jj] = oacc1[jj] + s1[jj] + bp[jj];
    }
  }
}

extern "C" void kernel_launch(void* const* d_in, const int* in_sizes, int n_in,
                              void* d_out, int out_size, void* d_ws, size_t ws_size,
                              hipStream_t stream) {
  const float* x   = (const float*)d_in[0];
  const float* Whx = (const float*)d_in[1];
  const float* Whh = (const float*)d_in[2];
  const float* Wph = (const float*)d_in[3];
  const float* Bh  = (const float*)d_in[4];
  const float* Bp  = (const float*)d_in[5];
  float* out = (float*)d_out;

  char* ws = (char*)d_ws;
  u64* h0         = (u64*)(ws);                   // 1 MB: h ping
  u64* h1         = (u64*)(ws + (1 << 20));       // 1 MB: h pong
  unsigned* flags = (unsigned*)(ws + (2 << 20));  // 8 groups x 32 step flags

  hipMemsetAsync(h0, 0, (size_t)kBt * kH * sizeof(unsigned short), stream);  // h_0 = 0
  hipMemsetAsync(flags, 0, 4096, stream);                                    // reset barrier

  dim3 grid(256), block(512);
  size_t lds = 155648;  // 128K h-stage + 24K zone
  hipLaunchKernelGGL(rnn_fused, grid, block, lds, stream,
                     x, Whx, Whh, Wph, Bh, Bp, out, h0, h1, flags);
}